// Round 4
// baseline (783.440 us; speedup 1.0000x reference)
//
#include <hip/hip_runtime.h>

#define DIM    2048
#define SEQ    2048
#define BATCH  4
#define NH     16
#define NKV    4
#define HD     128
#define QKVN   3072
#define ROWS   (BATCH*SEQ)   // 8192

typedef __bf16 bf16;
typedef __bf16 bf16x2 __attribute__((ext_vector_type(2)));
typedef __bf16 bf16x4 __attribute__((ext_vector_type(4)));
typedef __bf16 bf16x8 __attribute__((ext_vector_type(8)));
typedef float  f32x4  __attribute__((ext_vector_type(4)));
typedef float  f32x16 __attribute__((ext_vector_type(16)));

typedef union { bf16x4 v; unsigned int u[2]; } b4u;
typedef union { bf16x8 v8; bf16x4 v4[2]; } b8u;

// scale(1/sqrt(128)) * log2(e) — folded into Q at rmsnorm time
#define SL2E 0.12752365234813963f

__device__ __forceinline__ void gload_lds16(const void* g, void* l) {
  __builtin_amdgcn_global_load_lds(
      (const __attribute__((address_space(1))) void*)g,
      (__attribute__((address_space(3))) void*)l, 16, 0, 0);
}

// ---------------- small prep kernels ----------------

__global__ void convert_f32_bf16(const float* __restrict__ in, bf16* __restrict__ out, int n) {
  int i = (blockIdx.x * 256 + threadIdx.x) * 4;
  if (i < n) {
    float4 v = *(const float4*)(in + i);
    bf16x4 t = {(bf16)v.x, (bf16)v.y, (bf16)v.z, (bf16)v.w};
    *(bf16x4*)(out + i) = t;
  }
}

// in [R][C] fp32 -> out [C][R] bf16
__global__ void transpose_w(const float* __restrict__ in, bf16* __restrict__ out, int R, int C) {
  __shared__ float t[64][65];
  int c0 = blockIdx.x * 64, r0 = blockIdx.y * 64;
  int tx = threadIdx.x & 63, ty = threadIdx.x >> 6;
  for (int i = ty; i < 64; i += 4) t[i][tx] = in[(size_t)(r0 + i) * C + c0 + tx];
  __syncthreads();
  for (int i = ty; i < 64; i += 4) out[(size_t)(c0 + i) * R + r0 + tx] = (bf16)t[tx][i];
}

// v [z][2048][128] bf16 -> vT [z][128][2048] bf16
__global__ void transpose_v(const bf16* __restrict__ vb, bf16* __restrict__ vT) {
  __shared__ bf16 t[64][65];
  int z = blockIdx.z;
  const bf16* in = vb + (size_t)z * SEQ * HD;
  bf16* out = vT + (size_t)z * HD * SEQ;
  int d0 = blockIdx.x * 64, s0 = blockIdx.y * 64;
  int tx = threadIdx.x & 63, ty = threadIdx.x >> 6;
  for (int i = ty; i < 64; i += 4) t[i][tx] = in[(size_t)(s0 + i) * HD + d0 + tx];
  __syncthreads();
  for (int i = ty; i < 64; i += 4) out[(size_t)(d0 + i) * SEQ + s0 + tx] = t[tx][i];
}

__global__ void rope_tables(float* __restrict__ cosT, float* __restrict__ sinT) {
  int idx = blockIdx.x * 256 + threadIdx.x;  // SEQ*64
  int s = idx >> 6, j = idx & 63;
  float inv = powf(10000.0f, -(float)j * (1.0f / 64.0f));
  float ang = (float)s * inv;
  cosT[idx] = cosf(ang);
  sinT[idx] = sinf(ang);
}

// ---------------- m97-style bf16 MFMA GEMM, B transposed ----------------
// C[M][N] = A[M][K] * BT[N][K]^T ; tiles 128x128, BK=32, 256 threads
template <typename OutT>
__global__ __launch_bounds__(256, 2) void gemm_bt(
    const bf16* __restrict__ A, const bf16* __restrict__ BT,
    OutT* __restrict__ C, int M, int N, int K) {
  __shared__ __align__(16) bf16 lA[128 * 32];
  __shared__ __align__(16) bf16 lB[128 * 32];
  const int tid = threadIdx.x;
  const int lane = tid & 63, wave = tid >> 6;
  const int quad = lane >> 4, l16 = lane & 15;
  const int tileM = blockIdx.y * 128, tileN = blockIdx.x * 128;
  const int wm = (wave >> 1) * 64, wn = (wave & 1) * 64;

  f32x4 acc[4][4] = {};

  for (int kt = 0; kt < K; kt += 32) {
    __syncthreads();
    {
      int g0 = tid, g1 = tid + 256;
      gload_lds16(A + (size_t)(tileM + (g0 >> 2)) * K + kt + (g0 & 3) * 8,
                  (char*)lA + wave * 1024);
      gload_lds16(A + (size_t)(tileM + (g1 >> 2)) * K + kt + (g1 & 3) * 8,
                  (char*)lA + 4096 + wave * 1024);
      gload_lds16(BT + (size_t)(tileN + (g0 >> 2)) * K + kt + (g0 & 3) * 8,
                  (char*)lB + wave * 1024);
      gload_lds16(BT + (size_t)(tileN + (g1 >> 2)) * K + kt + (g1 & 3) * 8,
                  (char*)lB + 4096 + wave * 1024);
    }
    __syncthreads();

    bf16x8 af[4], bfr[4];
#pragma unroll
    for (int i = 0; i < 4; ++i)
      af[i] = *(const bf16x8*)&lA[(wm + i * 16 + l16) * 32 + quad * 8];
#pragma unroll
    for (int j = 0; j < 4; ++j)
      bfr[j] = *(const bf16x8*)&lB[(wn + j * 16 + l16) * 32 + quad * 8];
#pragma unroll
    for (int i = 0; i < 4; ++i)
#pragma unroll
      for (int j = 0; j < 4; ++j)
        acc[i][j] = __builtin_amdgcn_mfma_f32_16x16x32_bf16(af[i], bfr[j], acc[i][j], 0, 0, 0);
  }

#pragma unroll
  for (int i = 0; i < 4; ++i)
#pragma unroll
    for (int j = 0; j < 4; ++j)
#pragma unroll
      for (int r = 0; r < 4; ++r) {
        int row = tileM + wm + i * 16 + quad * 4 + r;
        int col = tileN + wn + j * 16 + l16;
        C[(size_t)row * N + col] = (OutT)acc[i][j][r];
      }
}

// ---------------- fused RMSNorm + RoPE + scatter ----------------
// qkv [8192][3072] bf16 -> q [B][NH][S][HD] (Q pre-scaled by SL2E), k/v [B][NKV][S][HD]
__global__ __launch_bounds__(256) void rmsnorm_rope(
    const bf16* __restrict__ qkv, const float* __restrict__ cosT,
    const float* __restrict__ sinT, bf16* __restrict__ qb,
    bf16* __restrict__ kb, bf16* __restrict__ vb) {
  int wave = threadIdx.x >> 6, lane = threadIdx.x & 63;
  int task = blockIdx.x * 4 + wave;          // row*24 + chunk
  int row = task / 24, chunk = task % 24;
  int b = row >> 11, s = row & 2047;

  const bf16* src = qkv + (size_t)row * QKVN + chunk * 128 + lane * 2;
  bf16x2 v = *(const bf16x2*)src;
  bf16 o0, o1;
  if (chunk >= 20) {  // V: passthrough
    o0 = v[0]; o1 = v[1];
  } else {            // Q/K: RMSNorm + RoPE
    float x0 = (float)v[0], x1 = (float)v[1];
    float ss = x0 * x0 + x1 * x1;
#pragma unroll
    for (int off = 1; off < 64; off <<= 1) ss += __shfl_xor(ss, off);
    float rms = rsqrtf(ss * (1.0f / 128.0f) + 1.1920929e-07f);
    x0 *= rms; x1 *= rms;
    float p0 = __shfl_xor(x0, 32), p1 = __shfl_xor(x1, 32);
    int j0 = (lane & 31) * 2;
    float c0 = cosT[s * 64 + j0], c1 = cosT[s * 64 + j0 + 1];
    float s0 = sinT[s * 64 + j0], s1 = sinT[s * 64 + j0 + 1];
    float r0, r1;
    if (lane < 32) { r0 = x0 * c0 + p0 * s0; r1 = x1 * c1 + p1 * s1; }
    else           { r0 = x0 * c0 - p0 * s0; r1 = x1 * c1 - p1 * s1; }
    if (chunk < 16) { r0 *= SL2E; r1 *= SL2E; }  // fold softmax scale*log2e into Q
    o0 = (bf16)r0; o1 = (bf16)r1;
  }
  bf16* dst;
  int d = lane * 2;
  if (chunk < 16)      dst = qb + ((size_t)(b * NH + chunk) * SEQ + s) * HD + d;
  else if (chunk < 20) dst = kb + ((size_t)(b * NKV + (chunk - 16)) * SEQ + s) * HD + d;
  else                 dst = vb + ((size_t)(b * NKV + (chunk - 20)) * SEQ + s) * HD + d;
  bf16x2 t = {o0, o1};
  *(bf16x2*)dst = t;
}

// ---------------- flash attention v4 ----------------
// 32x32x16 MFMA, S^T orientation, no-max softmax (Q pre-scaled by SL2E),
// P in registers (half-wave shfl). kv-tile 64 -> LDS 32KB -> 4 blocks/CU
// (16 waves) for latency hiding. Grid 16x16x4, heavy q-tiles first.
// q [B][NH][S][HD], k [B][NKV][S][HD], vT [B][NKV][HD][S] -> y [B*S][DIM]
__global__ __launch_bounds__(256, 4) void attn_kernel(
    const bf16* __restrict__ qb, const bf16* __restrict__ kb,
    const bf16* __restrict__ vTb, bf16* __restrict__ y) {
  __shared__ __align__(16) char sm[32768];
  bf16* lK = (bf16*)sm;            // K tile [64 kv][128 d], granule g at g^(row&15)
  bf16* lV = (bf16*)(sm + 16384);  // V^T tile [128 d][64 kv], granule g at g^(row&7)

  const int tid = threadIdx.x;
  const int lane = tid & 63, wave = tid >> 6;
  const int l32 = lane & 31, h = lane >> 5;
  const int qt = 15 - (int)blockIdx.x;      // heavy q-tiles dispatched first
  const int hh = blockIdx.y, b = blockIdx.z;
  const int kvh = hh >> 2;

  const bf16* qh = qb + (size_t)(b * NH + hh) * SEQ * HD;
  const bf16* kh = kb + (size_t)(b * NKV + kvh) * SEQ * HD;
  const bf16* vh = vTb + (size_t)(b * NKV + kvh) * HD * SEQ;

  const int qtile = qt * 128;
  const int rS = qtile + wave * 32;          // wave's first q row
  const int qrow = rS + l32;                 // this lane's q row

  // Q fragments (B-operand): [n=q on l32][k = ks*16 + h*8 + j]
  bf16x8 qf[8];
#pragma unroll
  for (int ks = 0; ks < 8; ++ks)
    qf[ks] = *(const bf16x8*)&qh[(size_t)qrow * HD + ks * 16 + h * 8];

  f32x16 oacc[4] = {};
  float psum = 0.f;

  for (int kv0 = 0; kv0 <= qtile + 64; kv0 += 64) {
    __syncthreads();
    // stage K [64][128] (insts 0-3) and V^T [128][64] (insts 4-7)
#pragma unroll
    for (int inst = 0; inst < 4; ++inst) {
      int slot = inst * 256 + tid;
      int R = slot >> 4;
      int gg = (slot & 15) ^ (R & 15);
      gload_lds16(kh + (size_t)(kv0 + R) * HD + gg * 8, (char*)lK + inst * 4096 + wave * 1024);
    }
#pragma unroll
    for (int inst = 0; inst < 4; ++inst) {
      int slot = inst * 256 + tid;
      int R = slot >> 3;
      int gg = (slot & 7) ^ (R & 7);
      gload_lds16(vh + (size_t)R * SEQ + kv0 + gg * 8, (char*)lV + inst * 4096 + wave * 1024);
    }
    __syncthreads();

#pragma unroll
    for (int kvb = 0; kvb < 2; ++kvb) {
      const int kvS = kv0 + kvb * 32;
      if (kvS <= rS) {   // else fully masked for this wave
        // S^T = K Q^T : A = K (m=kv on l32), B = Q (n=q on l32)
        f32x16 sacc = {};
#pragma unroll
        for (int ks = 0; ks < 8; ++ks) {
          int row = kvb * 32 + l32;
          const bf16x8 af = *(const bf16x8*)&lK[row * 128 + (((ks * 2 + h) ^ (row & 15)) << 3)];
          sacc = __builtin_amdgcn_mfma_f32_32x32x16_bf16(af, qf[ks], sacc, 0, 0, 0);
        }
        // no-max softmax: p = exp2(sacc) (Q carries scale*log2e)
        float p[16];
        const bool msk = (kvS == rS);  // diagonal 32x32 block
#pragma unroll
        for (int r = 0; r < 16; ++r) {
          float v = sacc[r];
          if (msk) {
            int kv = kvS + (r & 3) + 4 * h + 8 * (r >> 2);
            if (kv > qrow) v = -1e30f;
          }
          float e = exp2f(v);
          p[r] = e;
          psum += e;
        }
        // pack 4-reg blocks to bf16x4 (C row blocks: kv = (r&3) + 4h + 8*(r>>2))
        b4u pk[4];
#pragma unroll
        for (int B = 0; B < 4; ++B) {
          bf16x4 t4 = {(bf16)p[4 * B], (bf16)p[4 * B + 1], (bf16)p[4 * B + 2], (bf16)p[4 * B + 3]};
          pk[B].v = t4;
        }
        // build PV A-frags (m=q on l32, k = 8h+j) via half-wave exchange
#pragma unroll
        for (int ss = 0; ss < 2; ++ss) {
          b4u own = pk[2 * ss + h];
          b4u send = pk[2 * ss + (h ^ 1)];
          b4u got;
          got.u[0] = __shfl_xor(send.u[0], 32);
          got.u[1] = __shfl_xor(send.u[1], 32);
          b8u fr;
          fr.v4[0] = h ? got.v : own.v;
          fr.v4[1] = h ? own.v : got.v;
          int gi = kvb * 4 + ss * 2 + h;  // 16B granule of V^T row (k-chunk)
#pragma unroll
          for (int nd = 0; nd < 4; ++nd) {
            int row = nd * 32 + l32;
            const bf16x8 vf = *(const bf16x8*)&lV[row * 64 + ((gi ^ (row & 7)) << 3)];
            oacc[nd] = __builtin_amdgcn_mfma_f32_32x32x16_bf16(fr.v8, vf, oacc[nd], 0, 0, 0);
          }
        }
      }
    }
  }

  // epilogue: lane holds O cols d=nd*32+l32, rows q_local=(r&3)+4h+8*(r>>2)
  float lsum = psum + __shfl_xor(psum, 32);
#pragma unroll
  for (int r = 0; r < 16; ++r) {
    int ql = (r & 3) + 4 * h + 8 * (r >> 2);
    float li = 1.0f / __shfl(lsum, ql);
    size_t base = ((size_t)(b * SEQ + qtile + wave * 32 + ql)) * DIM + hh * HD;
#pragma unroll
    for (int nd = 0; nd < 4; ++nd)
      y[base + nd * 32 + l32] = (bf16)(oacc[nd][r] * li);
  }
}

// ---------------- launcher ----------------

extern "C" void kernel_launch(void* const* d_in, const int* in_sizes, int n_in,
                              void* d_out, int out_size, void* d_ws, size_t ws_size,
                              hipStream_t stream) {
  const float* x    = (const float*)d_in[0];
  const float* Wqkv = (const float*)d_in[1];
  const float* Wout = (const float*)d_in[2];
  float* out = (float*)d_out;

  char* w = (char*)d_ws;
  auto carve = [&](size_t bytes) -> char* {
    char* p = w;
    w += (bytes + 255) & ~(size_t)255;
    return p;
  };
  bf16* xb   = (bf16*)carve((size_t)ROWS * DIM * 2);        // 32 MB; later aliased by qbuf
  bf16* WqT  = (bf16*)carve((size_t)QKVN * DIM * 2);        // 12 MB; later aliased by vT
  bf16* WoT  = (bf16*)carve((size_t)DIM * DIM * 2);         // 8 MB
  bf16* qkv  = (bf16*)carve((size_t)ROWS * QKVN * 2);       // 48 MB; later aliased by ybuf
  bf16* kbuf = (bf16*)carve((size_t)BATCH * NKV * SEQ * HD * 2);
  bf16* vbuf = (bf16*)carve((size_t)BATCH * NKV * SEQ * HD * 2);
  float* cosT = (float*)carve((size_t)SEQ * 64 * 4);
  float* sinT = (float*)carve((size_t)SEQ * 64 * 4);

  bf16* qbuf = xb;    // xb dead after GEMM1
  bf16* vT   = WqT;   // WqT dead after GEMM1
  bf16* ybuf = qkv;   // qkv dead after rmsnorm_rope

  convert_f32_bf16<<<ROWS * DIM / 1024, 256, 0, stream>>>(x, xb, ROWS * DIM);
  transpose_w<<<dim3(QKVN / 64, DIM / 64), 256, 0, stream>>>(Wqkv, WqT, DIM, QKVN);
  transpose_w<<<dim3(DIM / 64, DIM / 64), 256, 0, stream>>>(Wout, WoT, DIM, DIM);
  rope_tables<<<SEQ * 64 / 256, 256, 0, stream>>>(cosT, sinT);

  gemm_bt<bf16><<<dim3(QKVN / 128, ROWS / 128), 256, 0, stream>>>(xb, WqT, qkv, ROWS, QKVN, DIM);
  rmsnorm_rope<<<ROWS * 24 / 4, 256, 0, stream>>>(qkv, cosT, sinT, qbuf, kbuf, vbuf);
  transpose_v<<<dim3(HD / 64, SEQ / 64, BATCH * NKV), 256, 0, stream>>>(vbuf, vT);
  attn_kernel<<<dim3(16, NH, BATCH), 256, 0, stream>>>(qbuf, kbuf, vT, ybuf);
  gemm_bt<float><<<dim3(DIM / 128, ROWS / 128), 256, 0, stream>>>(ybuf, WoT, out, ROWS, DIM, DIM);
}